// Round 1
// baseline (172.246 us; speedup 1.0000x reference)
//
#include <hip/hip_runtime.h>

// OverlappingEdgeProcessor: x (4,6,16,512,512) f32.
// out = x everywhere except 4-wide edge strips, which blend with the
// adjacent face's matching strip (weights linspace(0,1,4) along the strip).
// Active (f,e,af,ae) after the shape-mismatch `continue` filter (no flips):
//   f0: e0<-F2 cols[508:], e1<-F3 cols[:4], e2<-F4 rows[h], e3<-F5 rows[h-508]
//   f1: e0<-F3 cols[508:], e1<-F2 cols[:4]
//   f2: e0<-F1 cols[508:], e1<-F0 cols[:4], e2<-F4 rows[508+h], e3<-F5 rows[h]
//   f3: e0<-F0 cols[508:], e1<-F1 cols[:4]
//   f4: e2<-F0 rows[h], e3<-F2 rows[h-508]
//   f5: e2<-F0 rows[508+h], e3<-F2 rows[h]
// Precedence inside a face (corners): e3 > e2 > e1 > e0 (later .set wins).

__device__ __forceinline__ float4 blend_t(float4 er, float4 ar, float t) {
  float u = 1.0f - t;
  return float4{er.x * t + ar.x * u, er.y * t + ar.y * u,
                er.z * t + ar.z * u, er.w * t + ar.w * u};
}
// left edge (w=0..3), weights on er = {0, 1/3, 2/3, 1}
__device__ __forceinline__ float4 blend_w01(float4 er, float4 ar) {
  const float a = 1.0f / 3.0f, b = 2.0f / 3.0f;
  return float4{ar.x, er.y * a + ar.y * b, er.z * b + ar.z * a, er.w};
}
// right edge (w=508..511), weights on er = {1, 2/3, 1/3, 0}
__device__ __forceinline__ float4 blend_w10(float4 er, float4 ar) {
  const float a = 1.0f / 3.0f, b = 2.0f / 3.0f;
  return float4{er.x, er.y * b + ar.y * a, er.z * a + ar.z * b, ar.w};
}

__global__ __launch_bounds__(256) void edge_blend_kernel(
    const float4* __restrict__ in, float4* __restrict__ out, int total4) {
  constexpr int W4 = 128;          // 512 floats / 4
  constexpr int PLANE = 512 * W4;  // float4 per (b,f,c) plane = 65536
  constexpr int FS = 16 * PLANE;   // face stride (C=16 planes) = 1048576
  const float inv3 = 1.0f / 3.0f;
  int stride = gridDim.x * blockDim.x;
  for (int idx = blockIdx.x * blockDim.x + threadIdx.x; idx < total4;
       idx += stride) {
    int w4 = idx & (W4 - 1);
    int rest = idx >> 7;        // (bf*16 + c)*512 + h
    int h = rest & 511;
    int bf = rest >> 13;        // b*6 + f   (< 24)
    int f = bf % 6;
    float4 v = in[idx];
    float4 r = v;
    int planeBase = idx - (h * W4 + w4);  // index of (b,f,c,0,0)

    if (f == 0) {
      if (h >= 508) {            // e3 <- F5 rows[h-508]
        int i = h - 508;
        r = blend_t(v, in[planeBase + 5 * FS + i * W4 + w4], (3 - i) * inv3);
      } else if (h < 4) {        // e2 <- F4 rows[h]
        r = blend_t(v, in[planeBase + 4 * FS + h * W4 + w4], h * inv3);
      } else if (w4 == W4 - 1) { // e1 <- F3 cols[0:4]
        r = blend_w10(v, in[planeBase + 3 * FS + h * W4]);
      } else if (w4 == 0) {      // e0 <- F2 cols[508:512]
        r = blend_w01(v, in[planeBase + 2 * FS + h * W4 + (W4 - 1)]);
      }
    } else if (f == 1) {
      if (w4 == 0) {             // e0 <- F3 cols[508:512]
        r = blend_w01(v, in[planeBase + 2 * FS + h * W4 + (W4 - 1)]);
      } else if (w4 == W4 - 1) { // e1 <- F2 cols[0:4]
        r = blend_w10(v, in[planeBase + 1 * FS + h * W4]);
      }
    } else if (f == 2) {
      if (h >= 508) {            // e3 <- F5 rows[h]
        int i = h - 508;
        r = blend_t(v, in[planeBase + 3 * FS + h * W4 + w4], (3 - i) * inv3);
      } else if (h < 4) {        // e2 <- F4 rows[508+h]
        r = blend_t(v, in[planeBase + 2 * FS + (508 + h) * W4 + w4], h * inv3);
      } else if (w4 == W4 - 1) { // e1 <- F0 cols[0:4]
        r = blend_w10(v, in[planeBase - 2 * FS + h * W4]);
      } else if (w4 == 0) {      // e0 <- F1 cols[508:512]
        r = blend_w01(v, in[planeBase - 1 * FS + h * W4 + (W4 - 1)]);
      }
    } else if (f == 3) {
      if (w4 == 0) {             // e0 <- F0 cols[508:512]
        r = blend_w01(v, in[planeBase - 3 * FS + h * W4 + (W4 - 1)]);
      } else if (w4 == W4 - 1) { // e1 <- F1 cols[0:4]
        r = blend_w10(v, in[planeBase - 2 * FS + h * W4]);
      }
    } else if (f == 4) {
      if (h >= 508) {            // e3 <- F2 rows[h-508]
        int i = h - 508;
        r = blend_t(v, in[planeBase - 2 * FS + i * W4 + w4], (3 - i) * inv3);
      } else if (h < 4) {        // e2 <- F0 rows[h]
        r = blend_t(v, in[planeBase - 4 * FS + h * W4 + w4], h * inv3);
      }
    } else {  // f == 5
      if (h >= 508) {            // e3 <- F2 rows[h]
        int i = h - 508;
        r = blend_t(v, in[planeBase - 3 * FS + h * W4 + w4], (3 - i) * inv3);
      } else if (h < 4) {        // e2 <- F0 rows[508+h]
        r = blend_t(v, in[planeBase - 5 * FS + (508 + h) * W4 + w4], h * inv3);
      }
    }
    out[idx] = r;
  }
}

extern "C" void kernel_launch(void* const* d_in, const int* in_sizes, int n_in,
                              void* d_out, int out_size, void* d_ws,
                              size_t ws_size, hipStream_t stream) {
  const float4* in = (const float4*)d_in[0];
  float4* out = (float4*)d_out;
  int total4 = in_sizes[0] / 4;  // 25,165,824
  const int block = 256;
  int blocks = (total4 + block - 1) / block;
  const int maxBlocks = 2048;  // 8 blocks/CU, grid-stride the rest
  if (blocks > maxBlocks) blocks = maxBlocks;
  hipLaunchKernelGGL(edge_blend_kernel, dim3(blocks), dim3(block), 0, stream,
                     in, out, total4);
}